// Round 4
// baseline (199.830 us; speedup 1.0000x reference)
//
#include <hip/hip_runtime.h>
#include <float.h>

#define N_NODES 4096
#define IN_FEAT 256
#define N_HEADS 8
#define N_HIDDEN 64
#define OUT_FEAT (N_HEADS * N_HIDDEN)  // 512
#define MAXE 512                        // deg ~ Binom(4096,.05): mean 205, sigma 14
#define NEG_SLOPE 0.2f
#define NH_ELEMS (N_NODES * IN_FEAT)    // 1048576

typedef _Float16 half8 __attribute__((ext_vector_type(8)));
typedef float floatx4 __attribute__((ext_vector_type(4)));
typedef float float8v __attribute__((ext_vector_type(8)));

// Monotone float<->uint key for atomicMax-based float max (handles negatives).
__device__ inline unsigned fkey(float f) {
  unsigned u = __float_as_uint(f);
  return (u & 0x80000000u) ? ~u : (u | 0x80000000u);
}
__device__ inline float fkey_inv(unsigned k) {
  unsigned u = (k & 0x80000000u) ? (k & 0x7fffffffu) : ~k;
  return __uint_as_float(u);
}

// ---------------- split H (then W) into fp16 hi+lo pairs ----------------
// X = Xh + Xl exactly to fp16 rounding; Markidis 3-product GEMM gives ~fp32 acc.
__global__ __launch_bounds__(256) void convert_split(
    const float* __restrict__ H, const float* __restrict__ W,
    _Float16* __restrict__ Xh, _Float16* __restrict__ Xl) {
  const int idx = (blockIdx.x * 256 + threadIdx.x) * 4;
  const float* src = (idx < NH_ELEMS) ? (H + idx) : (W + (idx - NH_ELEMS));
  float4 v = *(const float4*)src;
  union { _Float16 h[4]; int2 d; } uh, ul;
  uh.h[0] = (_Float16)v.x; uh.h[1] = (_Float16)v.y;
  uh.h[2] = (_Float16)v.z; uh.h[3] = (_Float16)v.w;
  ul.h[0] = (_Float16)(v.x - (float)uh.h[0]);
  ul.h[1] = (_Float16)(v.y - (float)uh.h[1]);
  ul.h[2] = (_Float16)(v.z - (float)uh.h[2]);
  ul.h[3] = (_Float16)(v.w - (float)uh.h[3]);
  *(int2*)(Xh + idx) = uh.d;
  *(int2*)(Xl + idx) = ul.d;
}

// ---------------- MFMA GEMM + fused epilogue ----------------
// Block (bi,bo): G-tile rows bi*64..+63, cols = head bo's 64 features, K=256
// fully reduced. Wave w owns rows bi*64+w*16..+15. Epilogue computes G16
// (fp16), el/er (dot with a_l/a_r), gsum (column sums, atomicAdd), and
// ermax (atomicMax on monotone keys) — all from the fp32 accumulators.
// Fragment layouts (validated in the round-2 MFMA kernel):
//   A: m=lane&15, k=(lane>>4)*8+j ; B: n=lane&15, k=(lane>>4)*8+j
//   C/D: row=(lane>>4)*4+reg, col=lane&15
__global__ __launch_bounds__(256) void gemm_mfma(
    const _Float16* __restrict__ Xh, const _Float16* __restrict__ Xl,
    const float* __restrict__ a,
    _Float16* __restrict__ G16, float* __restrict__ el, float* __restrict__ er,
    float* __restrict__ gsum, unsigned* __restrict__ ermax_keys) {
  const int t = threadIdx.x;
  const int w = t >> 6, l = t & 63;
  const int n16 = l & 15, q = l >> 4;
  const int bi = blockIdx.x, bo = blockIdx.y;
  const int m0 = bi * 64 + w * 16;

  const _Float16* Wh = Xh + NH_ELEMS;
  const _Float16* Wl = Xl + NH_ELEMS;

  floatx4 acc[4];
#pragma unroll
  for (int ct = 0; ct < 4; ++ct) acc[ct] = (floatx4)0.f;

  const _Float16* arow_h = Xh + (size_t)(m0 + n16) * IN_FEAT + q * 8;
  const _Float16* arow_l = Xl + (size_t)(m0 + n16) * IN_FEAT + q * 8;

#pragma unroll
  for (int ks = 0; ks < 8; ++ks) {
    half8 Afh = *(const half8*)(arow_h + ks * 32);
    half8 Afl = *(const half8*)(arow_l + ks * 32);
#pragma unroll
    for (int ct = 0; ct < 4; ++ct) {
      const size_t woff = (size_t)(bo * 64 + ct * 16 + n16) * IN_FEAT + ks * 32 + q * 8;
      half8 Bfh = *(const half8*)(Wh + woff);
      half8 Bfl = *(const half8*)(Wl + woff);
      acc[ct] = __builtin_amdgcn_mfma_f32_16x16x32_f16(Afh, Bfh, acc[ct], 0, 0, 0);
      acc[ct] = __builtin_amdgcn_mfma_f32_16x16x32_f16(Afl, Bfh, acc[ct], 0, 0, 0);
      acc[ct] = __builtin_amdgcn_mfma_f32_16x16x32_f16(Afh, Bfl, acc[ct], 0, 0, 0);
    }
  }

  // ---- epilogue ----
  float aLv[4], aRv[4];
#pragma unroll
  for (int ct = 0; ct < 4; ++ct) {
    aLv[ct] = a[ct * 16 + n16];
    aRv[ct] = a[64 + ct * 16 + n16];
  }

  // el/er per row (row = m0 + q*4 + reg): dot over 64 cols.
  float erv[4];
#pragma unroll
  for (int reg = 0; reg < 4; ++reg) {
    float sl = 0.f, sr = 0.f;
#pragma unroll
    for (int ct = 0; ct < 4; ++ct) {
      sl = fmaf(acc[ct][reg], aLv[ct], sl);
      sr = fmaf(acc[ct][reg], aRv[ct], sr);
    }
#pragma unroll
    for (int off = 1; off < 16; off <<= 1) {
      sl += __shfl_xor(sl, off);
      sr += __shfl_xor(sr, off);
    }
    erv[reg] = sr;
    if (n16 == 0) {
      const int rowi = m0 + q * 4 + reg;
      el[(size_t)rowi * N_HEADS + bo] = sl;
      er[(size_t)rowi * N_HEADS + bo] = sr;
    }
  }

  // ermax[bo] via one atomicMax per wave.
  {
    float mx = fmaxf(fmaxf(erv[0], erv[1]), fmaxf(erv[2], erv[3]));
    mx = fmaxf(mx, __shfl_xor(mx, 16));
    mx = fmaxf(mx, __shfl_xor(mx, 32));
    if (l == 0) atomicMax(ermax_keys + bo, fkey(mx));
  }

  // gsum column partials: one atomicAdd per (ct, col) per wave.
#pragma unroll
  for (int ct = 0; ct < 4; ++ct) {
    float s = acc[ct][0] + acc[ct][1] + acc[ct][2] + acc[ct][3];
    s += __shfl_xor(s, 16);
    s += __shfl_xor(s, 32);
    if (l < 16) atomicAdd(gsum + bo * 64 + ct * 16 + n16, s);
  }

  // G16 store.
#pragma unroll
  for (int ct = 0; ct < 4; ++ct)
#pragma unroll
    for (int reg = 0; reg < 4; ++reg)
      G16[(size_t)(m0 + q * 4 + reg) * OUT_FEAT + bo * 64 + ct * 16 + n16] =
          (_Float16)acc[ct][reg];
}

// ---------------- sparse attention, fp16 gather ----------------
// One block per row i. m_h = max(0, el[i,h]+ermax[h]) upper-bounds every
// lrelu(el+er) and the non-edge value 0, so all exp() args <= 0.
// out[i,h,:] = ( sum_edges (w_j - em)*g16[j,h,:] + em*Gsum[h,:] ) / Z,
// Z = sum_edges w_j + (N-deg)*em.
__global__ __launch_bounds__(256, 8) void attn_sparse(
    const float* __restrict__ adj, const _Float16* __restrict__ G16,
    const float* __restrict__ el, const float* __restrict__ er,
    const unsigned* __restrict__ ermax_keys, const float* __restrict__ gsum,
    float* __restrict__ out) {
  __shared__ int jlist[MAXE];              // 2 KB
  __shared__ _Float16 w16[MAXE * N_HEADS]; // 8 KB
  __shared__ float accp[4][OUT_FEAT];      // 8 KB
  __shared__ float el_s[N_HEADS], ermax_s[N_HEADS];
  __shared__ float zw[4][N_HEADS];
  __shared__ float em_s[N_HEADS], invz_s[N_HEADS];
  __shared__ int cnt;

  const int i = blockIdx.x;
  const int t = threadIdx.x;
  if (t == 0) cnt = 0;
  if (t < N_HEADS) {
    el_s[t] = el[(size_t)i * N_HEADS + t];
    ermax_s[t] = fkey_inv(ermax_keys[t]);
  }
  __syncthreads();

  // Phase 1: compact the adjacency row into an edge list.
  const float* row = adj + (size_t)i * N_NODES;
#pragma unroll
  for (int q = 0; q < 4; ++q) {
    int j0 = (q * 256 + t) * 4;
    float4 v = *(const float4*)(row + j0);
    if (v.x != 0.f) { int p = atomicAdd(&cnt, 1); if (p < MAXE) jlist[p] = j0; }
    if (v.y != 0.f) { int p = atomicAdd(&cnt, 1); if (p < MAXE) jlist[p] = j0 + 1; }
    if (v.z != 0.f) { int p = atomicAdd(&cnt, 1); if (p < MAXE) jlist[p] = j0 + 2; }
    if (v.w != 0.f) { int p = atomicAdd(&cnt, 1); if (p < MAXE) jlist[p] = j0 + 3; }
  }
  __syncthreads();
  const int deg = min(cnt, MAXE);

  // Phase 2: w = exp(lrelu(el+er) - m), fp16 into LDS; fp32 Z partials.
  const int h2 = t & 7;
  const float m_h = fmaxf(0.f, el_s[h2] + ermax_s[h2]);
  const float em_h = __expf(-m_h);
  float zacc = 0.f;
  for (int jj = t >> 3; jj < deg; jj += 32) {
    int j = jlist[jj];
    float x = el_s[h2] + er[(size_t)j * N_HEADS + h2];
    x = fmaxf(x, NEG_SLOPE * x);
    float wv = __expf(x - m_h);
    zacc += wv;
    w16[jj * N_HEADS + h2] = (_Float16)wv;
  }
#pragma unroll
  for (int off = 8; off < 64; off <<= 1) zacc += __shfl_xor(zacc, off);
  if ((t & 63) < 8) zw[t >> 6][t & 7] = zacc;
  __syncthreads();
  if (t < 8) {
    float Z = zw[0][t] + zw[1][t] + zw[2][t] + zw[3][t] +
              (float)(N_NODES - deg) * em_h;  // h2 == t here
    invz_s[t] = 1.f / Z;
    em_s[t] = em_h;
  }

  // Phase 3: gather-accumulate. Wave wv4 handles edges jj === wv4 (mod 4).
  // Lane map: hh=(t>>3)&7, lq=t&7 -> each wave reads a full 1KB G16 row.
  const int wv4 = t >> 6;
  const int hh = (t >> 3) & 7;
  const int lq = t & 7;
  const float m_hh = fmaxf(0.f, el_s[hh] + ermax_s[hh]);
  const float em = __expf(-m_hh);
  float8v accv = (float8v)0.f;

  int jj = wv4;
  float c_cur = 0.f;
  half8 g_cur = (half8)(_Float16)0.f;
  if (jj < deg) {
    int j = jlist[jj];
    c_cur = (float)w16[jj * N_HEADS + hh] - em;
    g_cur = *(const half8*)(G16 + (size_t)j * OUT_FEAT + hh * 64 + lq * 8);
  }
  while (jj < deg) {
    int jn = jj + 4;
    float c_n = 0.f;
    half8 g_n = g_cur;
    if (jn < deg) {
      int j = jlist[jn];
      c_n = (float)w16[jn * N_HEADS + hh] - em;
      g_n = *(const half8*)(G16 + (size_t)j * OUT_FEAT + hh * 64 + lq * 8);
    }
    accv += (float8v)c_cur * __builtin_convertvector(g_cur, float8v);
    jj = jn; c_cur = c_n; g_cur = g_n;
  }
  {
    float4 a0 = make_float4(accv[0], accv[1], accv[2], accv[3]);
    float4 a1 = make_float4(accv[4], accv[5], accv[6], accv[7]);
    *(float4*)&accp[wv4][hh * 64 + lq * 8] = a0;
    *(float4*)&accp[wv4][hh * 64 + lq * 8 + 4] = a1;
  }
  __syncthreads();

  // Phase 4: reduce 4 wave-partials, add em*Gsum correction, normalize.
  {
    const int c0 = t * 2;
    const int hf = c0 >> 6;
    float2 s = make_float2(0.f, 0.f);
#pragma unroll
    for (int g = 0; g < 4; ++g) {
      float2 p = *(const float2*)&accp[g][c0];
      s.x += p.x; s.y += p.y;
    }
    float2 gs = *(const float2*)(gsum + c0);
    const float emf = em_s[hf], iz = invz_s[hf];
    float2 o = make_float2((s.x + emf * gs.x) * iz, (s.y + emf * gs.y) * iz);
    *(float2*)(out + (size_t)i * OUT_FEAT + c0) = o;
  }
}

extern "C" void kernel_launch(void* const* d_in, const int* in_sizes, int n_in,
                              void* d_out, int out_size, void* d_ws, size_t ws_size,
                              hipStream_t stream) {
  const float* h   = (const float*)d_in[0];
  const float* adj = (const float*)d_in[1];
  const float* W   = (const float*)d_in[2];
  const float* a   = (const float*)d_in[3];
  float* out = (float*)d_out;

  char* ws = (char*)d_ws;
  _Float16* G16        = (_Float16*)ws;                              // 4 MB
  _Float16* Xh         = (_Float16*)(ws + 4u * 1024 * 1024);         // 2.25 MB
  _Float16* Xl         = (_Float16*)(ws + 6656u * 1024);             // 2.25 MB (6.5 MB off)
  float*    el         = (float*)(ws + 9216u * 1024);                // 128 KB (9 MB off)
  float*    er         = (float*)(ws + 9344u * 1024);                // 128 KB
  float*    gsum       = (float*)(ws + 9728u * 1024);                // 2 KB (9.5 MB off)
  unsigned* ermax_keys = (unsigned*)(ws + 9728u * 1024 + 2048);      // 32 B

  // zero gsum (512 floats) + ermax keys (8 uints, key 0 == -max) in one shot
  hipMemsetAsync(gsum, 0, 2048 + 32, stream);
  convert_split<<<dim3(1152), 256, 0, stream>>>(h, W, Xh, Xl);
  gemm_mfma<<<dim3(64, 8), 256, 0, stream>>>(Xh, Xl, a, G16, el, er, gsum, ermax_keys);
  attn_sparse<<<dim3(N_NODES), 256, 0, stream>>>(adj, G16, el, er, ermax_keys, gsum, out);
}

// Round 5
// 179.804 us; speedup vs baseline: 1.1114x; 1.1114x over previous
//
#include <hip/hip_runtime.h>
#include <float.h>

#define N_NODES 4096
#define IN_FEAT 256
#define N_HEADS 8
#define N_HIDDEN 64
#define OUT_FEAT (N_HEADS * N_HIDDEN)  // 512
#define MAXE 512                        // deg ~ Binom(4096,.05): mean 205, sigma 14
#define NEG_SLOPE 0.2f

typedef _Float16 half8 __attribute__((ext_vector_type(8)));
typedef float floatx4 __attribute__((ext_vector_type(4)));
typedef float float8v __attribute__((ext_vector_type(8)));

// Monotone float<->uint key for atomicMax-based float max (handles negatives).
__device__ inline unsigned fkey(float f) {
  unsigned u = __float_as_uint(f);
  return (u & 0x80000000u) ? ~u : (u | 0x80000000u);
}
__device__ inline float fkey_inv(unsigned k) {
  unsigned u = (k & 0x80000000u) ? (k & 0x7fffffffu) : ~k;
  return __uint_as_float(u);
}

// ---------------- fused producer: MFMA GEMM (Markidis split) + epilogue ----
// Block (bi,bo): rows bi*64..+63 x head bo's 64 features, K=256 in 4 chunks.
// H/W staged fp32->LDS as pre-split fp16 hi/lo; fragments via ds_read_b128.
// Epilogue (from validated R4 kernel): G16, el/er, gsum (atomicAdd),
// ermax (atomicMax on monotone keys).
// Fragment layouts: A/B: idx=lane&15, k=(lane>>4)*8+j; C/D: row=(lane>>4)*4+reg, col=lane&15.
__global__ __launch_bounds__(256) void gemm_fused(
    const float* __restrict__ H, const float* __restrict__ Wt,
    const float* __restrict__ a,
    _Float16* __restrict__ G16, float* __restrict__ el, float* __restrict__ er,
    float* __restrict__ gsum, unsigned* __restrict__ ermax_keys) {
  __shared__ _Float16 Ah[64][72], Al[64][72];  // 9216 B each
  __shared__ _Float16 Bh[64][72], Bl[64][72];  // total 36 KB
  const int t = threadIdx.x;
  const int w = t >> 6, l = t & 63;
  const int n16 = l & 15, q = l >> 4;
  const int bi = blockIdx.x, bo = blockIdx.y;
  const int m0 = bi * 64 + w * 16;

  floatx4 acc[4];
#pragma unroll
  for (int ct = 0; ct < 4; ++ct) acc[ct] = (floatx4)0.f;

  for (int kc = 0; kc < 4; ++kc) {
    if (kc) __syncthreads();  // drain reads of previous chunk before overwrite
    // ---- stage: 64x64 fp32 tiles of H and W, split to fp16 hi/lo ----
#pragma unroll
    for (int p = 0; p < 4; ++p) {
      const int idx = p * 256 + t;
      const int r = idx >> 4;
      const int c4 = (idx & 15) * 4;
      float4 hv = *(const float4*)(H + (size_t)(bi * 64 + r) * IN_FEAT + kc * 64 + c4);
      float4 wv = *(const float4*)(Wt + (size_t)(bo * 64 + r) * IN_FEAT + kc * 64 + c4);
      union { _Float16 h[4]; int2 d; } hh_, hl_, wh_, wl_;
      hh_.h[0] = (_Float16)hv.x; hh_.h[1] = (_Float16)hv.y;
      hh_.h[2] = (_Float16)hv.z; hh_.h[3] = (_Float16)hv.w;
      hl_.h[0] = (_Float16)(hv.x - (float)hh_.h[0]);
      hl_.h[1] = (_Float16)(hv.y - (float)hh_.h[1]);
      hl_.h[2] = (_Float16)(hv.z - (float)hh_.h[2]);
      hl_.h[3] = (_Float16)(hv.w - (float)hh_.h[3]);
      wh_.h[0] = (_Float16)wv.x; wh_.h[1] = (_Float16)wv.y;
      wh_.h[2] = (_Float16)wv.z; wh_.h[3] = (_Float16)wv.w;
      wl_.h[0] = (_Float16)(wv.x - (float)wh_.h[0]);
      wl_.h[1] = (_Float16)(wv.y - (float)wh_.h[1]);
      wl_.h[2] = (_Float16)(wv.z - (float)wh_.h[2]);
      wl_.h[3] = (_Float16)(wv.w - (float)wh_.h[3]);
      *(int2*)&Ah[r][c4] = hh_.d;
      *(int2*)&Al[r][c4] = hl_.d;
      *(int2*)&Bh[r][c4] = wh_.d;
      *(int2*)&Bl[r][c4] = wl_.d;
    }
    __syncthreads();
    // ---- compute: 2 k-steps of 32, 3-term Markidis per ct ----
#pragma unroll
    for (int ks = 0; ks < 2; ++ks) {
      half8 Afh = *(const half8*)&Ah[w * 16 + n16][ks * 32 + q * 8];
      half8 Afl = *(const half8*)&Al[w * 16 + n16][ks * 32 + q * 8];
#pragma unroll
      for (int ct = 0; ct < 4; ++ct) {
        half8 Bfh = *(const half8*)&Bh[ct * 16 + n16][ks * 32 + q * 8];
        half8 Bfl = *(const half8*)&Bl[ct * 16 + n16][ks * 32 + q * 8];
        acc[ct] = __builtin_amdgcn_mfma_f32_16x16x32_f16(Afh, Bfh, acc[ct], 0, 0, 0);
        acc[ct] = __builtin_amdgcn_mfma_f32_16x16x32_f16(Afl, Bfh, acc[ct], 0, 0, 0);
        acc[ct] = __builtin_amdgcn_mfma_f32_16x16x32_f16(Afh, Bfl, acc[ct], 0, 0, 0);
      }
    }
  }

  // ---- epilogue (identical math to validated R4 kernel) ----
  float aLv[4], aRv[4];
#pragma unroll
  for (int ct = 0; ct < 4; ++ct) {
    aLv[ct] = a[ct * 16 + n16];
    aRv[ct] = a[64 + ct * 16 + n16];
  }

  float erv[4];
#pragma unroll
  for (int reg = 0; reg < 4; ++reg) {
    float sl = 0.f, sr = 0.f;
#pragma unroll
    for (int ct = 0; ct < 4; ++ct) {
      sl = fmaf(acc[ct][reg], aLv[ct], sl);
      sr = fmaf(acc[ct][reg], aRv[ct], sr);
    }
#pragma unroll
    for (int off = 1; off < 16; off <<= 1) {
      sl += __shfl_xor(sl, off);
      sr += __shfl_xor(sr, off);
    }
    erv[reg] = sr;
    if (n16 == 0) {
      const int rowi = m0 + q * 4 + reg;
      el[(size_t)rowi * N_HEADS + bo] = sl;
      er[(size_t)rowi * N_HEADS + bo] = sr;
    }
  }

  {
    float mx = fmaxf(fmaxf(erv[0], erv[1]), fmaxf(erv[2], erv[3]));
    mx = fmaxf(mx, __shfl_xor(mx, 16));
    mx = fmaxf(mx, __shfl_xor(mx, 32));
    if (l == 0) atomicMax(ermax_keys + bo, fkey(mx));
  }

#pragma unroll
  for (int ct = 0; ct < 4; ++ct) {
    float s = acc[ct][0] + acc[ct][1] + acc[ct][2] + acc[ct][3];
    s += __shfl_xor(s, 16);
    s += __shfl_xor(s, 32);
    if (l < 16) atomicAdd(gsum + bo * 64 + ct * 16 + n16, s);
  }

#pragma unroll
  for (int ct = 0; ct < 4; ++ct)
#pragma unroll
    for (int reg = 0; reg < 4; ++reg)
      G16[(size_t)(m0 + q * 4 + reg) * OUT_FEAT + bo * 64 + ct * 16 + n16] =
          (_Float16)acc[ct][reg];
}

// ---------------- sparse attention, fp16 gather ----------------
// One block per row i. m_h = max(0, el[i,h]+ermax[h]) upper-bounds every
// lrelu(el+er) and the non-edge value 0, so all exp() args <= 0.
// out[i,h,:] = ( sum_edges (w_j - em)*g16[j,h,:] + em*Gsum[h,:] ) / Z,
// Z = sum_edges w_j + (N-deg)*em.
__global__ __launch_bounds__(256, 8) void attn_sparse(
    const float* __restrict__ adj, const _Float16* __restrict__ G16,
    const float* __restrict__ el, const float* __restrict__ er,
    const unsigned* __restrict__ ermax_keys, const float* __restrict__ gsum,
    float* __restrict__ out) {
  __shared__ int jlist[MAXE];              // 2 KB
  __shared__ _Float16 w16[MAXE * N_HEADS]; // 8 KB
  __shared__ float accp[4][OUT_FEAT];      // 8 KB
  __shared__ float el_s[N_HEADS], ermax_s[N_HEADS];
  __shared__ float zw[4][N_HEADS];
  __shared__ float em_s[N_HEADS], invz_s[N_HEADS];
  __shared__ int cnt;

  const int i = blockIdx.x;
  const int t = threadIdx.x;
  if (t == 0) cnt = 0;
  if (t < N_HEADS) {
    el_s[t] = el[(size_t)i * N_HEADS + t];
    ermax_s[t] = fkey_inv(ermax_keys[t]);
  }
  __syncthreads();

  // Phase 1: compact the adjacency row into an edge list.
  const float* row = adj + (size_t)i * N_NODES;
#pragma unroll
  for (int q = 0; q < 4; ++q) {
    int j0 = (q * 256 + t) * 4;
    float4 v = *(const float4*)(row + j0);
    if (v.x != 0.f) { int p = atomicAdd(&cnt, 1); if (p < MAXE) jlist[p] = j0; }
    if (v.y != 0.f) { int p = atomicAdd(&cnt, 1); if (p < MAXE) jlist[p] = j0 + 1; }
    if (v.z != 0.f) { int p = atomicAdd(&cnt, 1); if (p < MAXE) jlist[p] = j0 + 2; }
    if (v.w != 0.f) { int p = atomicAdd(&cnt, 1); if (p < MAXE) jlist[p] = j0 + 3; }
  }
  __syncthreads();
  const int deg = min(cnt, MAXE);

  // Phase 2: w = exp(lrelu(el+er) - m), fp16 into LDS; fp32 Z partials.
  const int h2 = t & 7;
  const float m_h = fmaxf(0.f, el_s[h2] + ermax_s[h2]);
  const float em_h = __expf(-m_h);
  float zacc = 0.f;
  for (int jj = t >> 3; jj < deg; jj += 32) {
    int j = jlist[jj];
    float x = el_s[h2] + er[(size_t)j * N_HEADS + h2];
    x = fmaxf(x, NEG_SLOPE * x);
    float wv = __expf(x - m_h);
    zacc += wv;
    w16[jj * N_HEADS + h2] = (_Float16)wv;
  }
#pragma unroll
  for (int off = 8; off < 64; off <<= 1) zacc += __shfl_xor(zacc, off);
  if ((t & 63) < 8) zw[t >> 6][t & 7] = zacc;
  __syncthreads();
  if (t < 8) {
    float Z = zw[0][t] + zw[1][t] + zw[2][t] + zw[3][t] +
              (float)(N_NODES - deg) * em_h;  // h2 == t here
    invz_s[t] = 1.f / Z;
    em_s[t] = em_h;
  }

  // Phase 3: gather-accumulate, two pipelined edge streams per wave.
  // Wave wv4 handles edges {base+wv4, base+wv4+4}, base += 8.
  // Lane map: hh=(t>>3)&7, lq=t&7 -> each wave reads full 1KB G16 rows.
  const int wv4 = t >> 6;
  const int hh = (t >> 3) & 7;
  const int lq = t & 7;
  const float m_hh = fmaxf(0.f, el_s[hh] + ermax_s[hh]);
  const float em = __expf(-m_hh);
  float8v accv = (float8v)0.f;

  if (deg > 0) {
    const int last = deg - 1;
    const int e0 = wv4, e1 = wv4 + 4;
    float c0 = 0.f, c1 = 0.f;
    half8 g0, g1;
    {
      int ja = jlist[min(e0, last)];
      int jb = jlist[min(e1, last)];
      if (e0 < deg) c0 = (float)w16[e0 * N_HEADS + hh] - em;
      if (e1 < deg) c1 = (float)w16[e1 * N_HEADS + hh] - em;
      g0 = *(const half8*)(G16 + (size_t)ja * OUT_FEAT + hh * 64 + lq * 8);
      g1 = *(const half8*)(G16 + (size_t)jb * OUT_FEAT + hh * 64 + lq * 8);
    }
    for (int base = 0; base < deg; base += 8) {
      float cn0 = 0.f, cn1 = 0.f;
      half8 gn0 = g0, gn1 = g1;
      if (base + 8 < deg) {
        const int n0 = base + 8 + wv4, n1 = base + 12 + wv4;
        int ja = jlist[min(n0, last)];
        int jb = jlist[min(n1, last)];
        if (n0 < deg) cn0 = (float)w16[n0 * N_HEADS + hh] - em;
        if (n1 < deg) cn1 = (float)w16[n1 * N_HEADS + hh] - em;
        gn0 = *(const half8*)(G16 + (size_t)ja * OUT_FEAT + hh * 64 + lq * 8);
        gn1 = *(const half8*)(G16 + (size_t)jb * OUT_FEAT + hh * 64 + lq * 8);
      }
      accv += (float8v)c0 * __builtin_convertvector(g0, float8v);
      accv += (float8v)c1 * __builtin_convertvector(g1, float8v);
      c0 = cn0; g0 = gn0; c1 = cn1; g1 = gn1;
    }
  }
  {
    float4 a0 = make_float4(accv[0], accv[1], accv[2], accv[3]);
    float4 a1 = make_float4(accv[4], accv[5], accv[6], accv[7]);
    *(float4*)&accp[wv4][hh * 64 + lq * 8] = a0;
    *(float4*)&accp[wv4][hh * 64 + lq * 8 + 4] = a1;
  }
  __syncthreads();

  // Phase 4: reduce 4 wave-partials, add em*Gsum correction, normalize.
  {
    const int c0 = t * 2;
    const int hf = c0 >> 6;
    float2 s = make_float2(0.f, 0.f);
#pragma unroll
    for (int g = 0; g < 4; ++g) {
      float2 p = *(const float2*)&accp[g][c0];
      s.x += p.x; s.y += p.y;
    }
    float2 gs = *(const float2*)(gsum + c0);
    const float emf = em_s[hf], iz = invz_s[hf];
    float2 o = make_float2((s.x + emf * gs.x) * iz, (s.y + emf * gs.y) * iz);
    *(float2*)(out + (size_t)i * OUT_FEAT + c0) = o;
  }
}

extern "C" void kernel_launch(void* const* d_in, const int* in_sizes, int n_in,
                              void* d_out, int out_size, void* d_ws, size_t ws_size,
                              hipStream_t stream) {
  const float* h   = (const float*)d_in[0];
  const float* adj = (const float*)d_in[1];
  const float* W   = (const float*)d_in[2];
  const float* a   = (const float*)d_in[3];
  float* out = (float*)d_out;

  char* ws = (char*)d_ws;
  _Float16* G16        = (_Float16*)ws;                          // 4 MB
  float*    el         = (float*)(ws + 4u * 1024 * 1024);        // 128 KB
  float*    er         = (float*)(ws + 4u * 1024 * 1024 + 128 * 1024);
  float*    gsum       = (float*)(ws + 4u * 1024 * 1024 + 256 * 1024);  // 2 KB
  unsigned* ermax_keys = (unsigned*)(ws + 4u * 1024 * 1024 + 258 * 1024);

  // zero gsum (512 floats) + ermax keys (8 uints; key 0 decodes below any real er)
  hipMemsetAsync(gsum, 0, 2048 + 32, stream);
  gemm_fused<<<dim3(64, 8), 256, 0, stream>>>(h, W, a, G16, el, er, gsum, ermax_keys);
  attn_sparse<<<dim3(N_NODES), 256, 0, stream>>>(adj, G16, el, er, ermax_keys, gsum, out);
}

// Round 6
// 174.254 us; speedup vs baseline: 1.1468x; 1.0319x over previous
//
#include <hip/hip_runtime.h>
#include <float.h>

#define N_NODES 4096
#define IN_FEAT 256
#define N_HEADS 8
#define N_HIDDEN 64
#define OUT_FEAT (N_HEADS * N_HIDDEN)  // 512
#define MAXE 512                        // deg ~ Binom(4096,.05): mean 205, sigma 14
#define NEG_SLOPE 0.2f
#define KC 128                          // GEMM K-chunk

typedef _Float16 half8 __attribute__((ext_vector_type(8)));
typedef _Float16 half2v __attribute__((ext_vector_type(2)));
typedef float floatx4 __attribute__((ext_vector_type(4)));

// Monotone float<->uint key for atomicMax-based float max (handles negatives).
__device__ inline unsigned fkey(float f) {
  unsigned u = __float_as_uint(f);
  return (u & 0x80000000u) ? ~u : (u | 0x80000000u);
}
__device__ inline float fkey_inv(unsigned k) {
  unsigned u = (k & 0x80000000u) ? (k & 0x7fffffffu) : ~k;
  return __uint_as_float(u);
}

// ---------------- fused producer: MFMA GEMM (Markidis split) + epilogue ----
// Block (bi,bo): rows bi*64..+63 x head bo's 64 features, K=256 in 2 chunks
// of 128. H/W staged fp32 -> fp16 hi/lo in XOR-swizzled LDS (16-B chunk c at
// position c ^ (row&7); row stride 128 halfs = 64 dw === 0 mod 32, so wave
// b128 fragment reads spread over all 32 banks -> conflict-free).
// Epilogue (validated R4/R5 math): el/er, gsum (atomicAdd), ermax
// (atomicMax on monotone keys); G16 stored via LDS bounce -> coalesced.
// Fragment layouts: A/B: idx=lane&15, k=(lane>>4)*8+j; C/D: row=(lane>>4)*4+reg, col=lane&15.
__global__ __launch_bounds__(256, 2) void gemm_fused(
    const float* __restrict__ H, const float* __restrict__ Wt,
    const float* __restrict__ a,
    _Float16* __restrict__ G16, float* __restrict__ el, float* __restrict__ er,
    float* __restrict__ gsum, unsigned* __restrict__ ermax_keys) {
  __shared__ _Float16 Ah[64 * KC];  // 16 KB each, 64 KB total
  __shared__ _Float16 Al[64 * KC];
  __shared__ _Float16 Bh[64 * KC];
  __shared__ _Float16 Bl[64 * KC];
  const int t = threadIdx.x;
  const int w = t >> 6, l = t & 63;
  const int n16 = l & 15, q = l >> 4;
  const int bi = blockIdx.x, bo = blockIdx.y;
  const int m0 = bi * 64 + w * 16;

  floatx4 acc[4];
#pragma unroll
  for (int ct = 0; ct < 4; ++ct) acc[ct] = (floatx4)0.f;

  for (int kc = 0; kc < 2; ++kc) {
    if (kc) __syncthreads();  // drain reads of previous chunk before overwrite
    // ---- stage: 64x128 fp32 tiles of H and W -> swizzled fp16 hi/lo ----
#pragma unroll
    for (int p = 0; p < 8; ++p) {
      const int idx = p * 256 + t;
      const int r = idx >> 5;            // 0..63
      const int c4 = (idx & 31) << 2;    // 0..124 (float col within chunk)
      const int dst = r * KC + (((idx & 31) >> 1) ^ (r & 7)) * 8 + (idx & 1) * 4;
      float4 hv = *(const float4*)(H + (size_t)(bi * 64 + r) * IN_FEAT + kc * KC + c4);
      float4 wv = *(const float4*)(Wt + (size_t)(bo * 64 + r) * IN_FEAT + kc * KC + c4);
      union { _Float16 h[4]; int2 d; } hh_, hl_, wh_, wl_;
      hh_.h[0] = (_Float16)hv.x; hh_.h[1] = (_Float16)hv.y;
      hh_.h[2] = (_Float16)hv.z; hh_.h[3] = (_Float16)hv.w;
      hl_.h[0] = (_Float16)(hv.x - (float)hh_.h[0]);
      hl_.h[1] = (_Float16)(hv.y - (float)hh_.h[1]);
      hl_.h[2] = (_Float16)(hv.z - (float)hh_.h[2]);
      hl_.h[3] = (_Float16)(hv.w - (float)hh_.h[3]);
      wh_.h[0] = (_Float16)wv.x; wh_.h[1] = (_Float16)wv.y;
      wh_.h[2] = (_Float16)wv.z; wh_.h[3] = (_Float16)wv.w;
      wl_.h[0] = (_Float16)(wv.x - (float)wh_.h[0]);
      wl_.h[1] = (_Float16)(wv.y - (float)wh_.h[1]);
      wl_.h[2] = (_Float16)(wv.z - (float)wh_.h[2]);
      wl_.h[3] = (_Float16)(wv.w - (float)wh_.h[3]);
      *(int2*)&Ah[dst] = hh_.d;
      *(int2*)&Al[dst] = hl_.d;
      *(int2*)&Bh[dst] = wh_.d;
      *(int2*)&Bl[dst] = wl_.d;
    }
    __syncthreads();
    // ---- compute: 4 k-steps of 32, 3-term Markidis per ct ----
#pragma unroll
    for (int ks = 0; ks < 4; ++ks) {
      const int aoff = (w * 16 + n16) * KC + (((ks << 2) + q) ^ (n16 & 7)) * 8;
      half8 Afh = *(const half8*)&Ah[aoff];
      half8 Afl = *(const half8*)&Al[aoff];
#pragma unroll
      for (int ct = 0; ct < 4; ++ct) {
        const int boff = (ct * 16 + n16) * KC + (((ks << 2) + q) ^ (n16 & 7)) * 8;
        half8 Bfh = *(const half8*)&Bh[boff];
        half8 Bfl = *(const half8*)&Bl[boff];
        acc[ct] = __builtin_amdgcn_mfma_f32_16x16x32_f16(Afh, Bfh, acc[ct], 0, 0, 0);
        acc[ct] = __builtin_amdgcn_mfma_f32_16x16x32_f16(Afl, Bfh, acc[ct], 0, 0, 0);
        acc[ct] = __builtin_amdgcn_mfma_f32_16x16x32_f16(Afh, Bfl, acc[ct], 0, 0, 0);
      }
    }
  }

  // ---- epilogue (identical math to validated R4/R5 kernels) ----
  float aLv[4], aRv[4];
#pragma unroll
  for (int ct = 0; ct < 4; ++ct) {
    aLv[ct] = a[ct * 16 + n16];
    aRv[ct] = a[64 + ct * 16 + n16];
  }

  float erv[4];
#pragma unroll
  for (int reg = 0; reg < 4; ++reg) {
    float sl = 0.f, sr = 0.f;
#pragma unroll
    for (int ct = 0; ct < 4; ++ct) {
      sl = fmaf(acc[ct][reg], aLv[ct], sl);
      sr = fmaf(acc[ct][reg], aRv[ct], sr);
    }
#pragma unroll
    for (int off = 1; off < 16; off <<= 1) {
      sl += __shfl_xor(sl, off);
      sr += __shfl_xor(sr, off);
    }
    erv[reg] = sr;
    if (n16 == 0) {
      const int rowi = m0 + q * 4 + reg;
      el[(size_t)rowi * N_HEADS + bo] = sl;
      er[(size_t)rowi * N_HEADS + bo] = sr;
    }
  }

  {
    float mx = fmaxf(fmaxf(erv[0], erv[1]), fmaxf(erv[2], erv[3]));
    mx = fmaxf(mx, __shfl_xor(mx, 16));
    mx = fmaxf(mx, __shfl_xor(mx, 32));
    if (l == 0) atomicMax(ermax_keys + bo, fkey(mx));
  }

#pragma unroll
  for (int ct = 0; ct < 4; ++ct) {
    float s = acc[ct][0] + acc[ct][1] + acc[ct][2] + acc[ct][3];
    s += __shfl_xor(s, 16);
    s += __shfl_xor(s, 32);
    if (l < 16) atomicAdd(gsum + bo * 64 + ct * 16 + n16, s);
  }

  // ---- G16 via LDS bounce -> coalesced dwordx4 stores ----
  __syncthreads();  // all MFMA reads of Ah done before reuse
  _Float16* LG = Ah;  // 64 rows x 72 halfs (9216 B <= 16 KB)
#pragma unroll
  for (int ct = 0; ct < 4; ++ct)
#pragma unroll
    for (int reg = 0; reg < 4; ++reg)
      LG[(w * 16 + q * 4 + reg) * 72 + ct * 16 + n16] = (_Float16)acc[ct][reg];
  __syncthreads();
  {
    const int row = t >> 2, ch = t & 3;  // 16 halfs (32 B) per thread
    int4 v0 = *(const int4*)&LG[row * 72 + ch * 16];
    int4 v1 = *(const int4*)&LG[row * 72 + ch * 16 + 8];
    _Float16* dst = G16 + (size_t)(bi * 64 + row) * OUT_FEAT + bo * 64 + ch * 16;
    *(int4*)dst = v0;
    *(int4*)(dst + 8) = v1;
  }
}

// ---------------- sparse attention, fp16 gather + v_dot2 ----------------
// One block per row i. m_h = max(0, el[i,h]+ermax[h]) upper-bounds every
// lrelu(el+er) and the non-edge value 0, so all exp() args <= 0.
// out[i,h,:] = ( sum_edges (w_j - em)*g16[j,h,:] + em*Gsum[h,:] ) / Z,
// Z = sum_edges w_j + (N-deg)*em.
__global__ __launch_bounds__(256, 8) void attn_sparse(
    const float* __restrict__ adj, const _Float16* __restrict__ G16,
    const float* __restrict__ el, const float* __restrict__ er,
    const unsigned* __restrict__ ermax_keys, const float* __restrict__ gsum,
    float* __restrict__ out) {
  __shared__ int jlist[MAXE];              // 2 KB
  __shared__ _Float16 w16[MAXE * N_HEADS]; // 8 KB
  __shared__ float accp[4][OUT_FEAT];      // 8 KB
  __shared__ float el_s[N_HEADS], ermax_s[N_HEADS];
  __shared__ float zw[4][N_HEADS];
  __shared__ float em_s[N_HEADS], invz_s[N_HEADS];
  __shared__ int cnt;

  const int i = blockIdx.x;
  const int t = threadIdx.x;
  if (t == 0) cnt = 0;
  if (t < N_HEADS) {
    el_s[t] = el[(size_t)i * N_HEADS + t];
    ermax_s[t] = fkey_inv(ermax_keys[t]);
  }
  __syncthreads();

  // Phase 1: compact the adjacency row into an edge list.
  const float* row = adj + (size_t)i * N_NODES;
#pragma unroll
  for (int q = 0; q < 4; ++q) {
    int j0 = (q * 256 + t) * 4;
    float4 v = *(const float4*)(row + j0);
    if (v.x != 0.f) { int p = atomicAdd(&cnt, 1); if (p < MAXE) jlist[p] = j0; }
    if (v.y != 0.f) { int p = atomicAdd(&cnt, 1); if (p < MAXE) jlist[p] = j0 + 1; }
    if (v.z != 0.f) { int p = atomicAdd(&cnt, 1); if (p < MAXE) jlist[p] = j0 + 2; }
    if (v.w != 0.f) { int p = atomicAdd(&cnt, 1); if (p < MAXE) jlist[p] = j0 + 3; }
  }
  __syncthreads();
  const int deg = min(cnt, MAXE);

  // Phase 2: w = exp(lrelu(el+er) - m), fp16 into LDS; fp32 Z partials.
  const int h2 = t & 7;
  const float m_h = fmaxf(0.f, el_s[h2] + ermax_s[h2]);
  const float em_h = __expf(-m_h);
  float zacc = 0.f;
  for (int jj = t >> 3; jj < deg; jj += 32) {
    int j = jlist[jj];
    float x = el_s[h2] + er[(size_t)j * N_HEADS + h2];
    x = fmaxf(x, NEG_SLOPE * x);
    float wv = __expf(x - m_h);
    zacc += wv;
    w16[jj * N_HEADS + h2] = (_Float16)wv;
  }
#pragma unroll
  for (int off = 8; off < 64; off <<= 1) zacc += __shfl_xor(zacc, off);
  if ((t & 63) < 8) zw[t >> 6][t & 7] = zacc;
  __syncthreads();
  if (t < 8) {
    float Z = zw[0][t] + zw[1][t] + zw[2][t] + zw[3][t] +
              (float)(N_NODES - deg) * em_h;  // h2 == t here
    invz_s[t] = 1.f / Z;
    em_s[t] = em_h;
  }

  // Phase 3: gather-accumulate, two pipelined edge streams per wave,
  // inner product via v_dot2_f32_f16 (c in fp16: error stays relative).
  const int wv4 = t >> 6;
  const int hh = (t >> 3) & 7;
  const int lq = t & 7;
  const float m_hh = fmaxf(0.f, el_s[hh] + ermax_s[hh]);
  const float em = __expf(-m_hh);
  const _Float16 em16 = (_Float16)em;
  float accf[8];
#pragma unroll
  for (int k = 0; k < 8; ++k) accf[k] = 0.f;

  if (deg > 0) {
    const int last = deg - 1;
    _Float16 c0 = (_Float16)0.f, c1 = (_Float16)0.f;
    half8 g0, g1;
    {
      const int e0 = wv4, e1 = wv4 + 4;
      int ja = jlist[min(e0, last)];
      int jb = jlist[min(e1, last)];
      if (e0 < deg) c0 = w16[e0 * N_HEADS + hh] - em16;
      if (e1 < deg) c1 = w16[e1 * N_HEADS + hh] - em16;
      g0 = *(const half8*)(G16 + (size_t)ja * OUT_FEAT + hh * 64 + lq * 8);
      g1 = *(const half8*)(G16 + (size_t)jb * OUT_FEAT + hh * 64 + lq * 8);
    }
    for (int base = 0; base < deg; base += 8) {
      _Float16 cn0 = (_Float16)0.f, cn1 = (_Float16)0.f;
      half8 gn0 = g0, gn1 = g1;
      if (base + 8 < deg) {
        const int n0 = base + 8 + wv4, n1 = base + 12 + wv4;
        int ja = jlist[min(n0, last)];
        int jb = jlist[min(n1, last)];
        if (n0 < deg) cn0 = w16[n0 * N_HEADS + hh] - em16;
        if (n1 < deg) cn1 = w16[n1 * N_HEADS + hh] - em16;
        gn0 = *(const half8*)(G16 + (size_t)ja * OUT_FEAT + hh * 64 + lq * 8);
        gn1 = *(const half8*)(G16 + (size_t)jb * OUT_FEAT + hh * 64 + lq * 8);
      }
#if __has_builtin(__builtin_amdgcn_fdot2)
      {
        half2v c2 = {c0, c1};
#pragma unroll
        for (int d = 0; d < 4; ++d) {
          half2v blo = {g0[2 * d], g1[2 * d]};
          half2v bhi = {g0[2 * d + 1], g1[2 * d + 1]};
          accf[2 * d] = __builtin_amdgcn_fdot2(c2, blo, accf[2 * d], false);
          accf[2 * d + 1] = __builtin_amdgcn_fdot2(c2, bhi, accf[2 * d + 1], false);
        }
      }
#else
      {
        const float f0 = (float)c0, f1 = (float)c1;
#pragma unroll
        for (int k = 0; k < 8; ++k) {
          accf[k] = fmaf(f0, (float)g0[k], accf[k]);
          accf[k] = fmaf(f1, (float)g1[k], accf[k]);
        }
      }
#endif
      c0 = cn0; c1 = cn1; g0 = gn0; g1 = gn1;
    }
  }
  {
    float4 a0 = make_float4(accf[0], accf[1], accf[2], accf[3]);
    float4 a1 = make_float4(accf[4], accf[5], accf[6], accf[7]);
    *(float4*)&accp[wv4][hh * 64 + lq * 8] = a0;
    *(float4*)&accp[wv4][hh * 64 + lq * 8 + 4] = a1;
  }
  __syncthreads();

  // Phase 4: reduce 4 wave-partials, add em*Gsum correction, normalize.
  {
    const int c0 = t * 2;
    const int hf = c0 >> 6;
    float2 s = make_float2(0.f, 0.f);
#pragma unroll
    for (int g = 0; g < 4; ++g) {
      float2 p = *(const float2*)&accp[g][c0];
      s.x += p.x; s.y += p.y;
    }
    float2 gs = *(const float2*)(gsum + c0);
    const float emf = em_s[hf], iz = invz_s[hf];
    float2 o = make_float2((s.x + emf * gs.x) * iz, (s.y + emf * gs.y) * iz);
    *(float2*)(out + (size_t)i * OUT_FEAT + c0) = o;
  }
}

extern "C" void kernel_launch(void* const* d_in, const int* in_sizes, int n_in,
                              void* d_out, int out_size, void* d_ws, size_t ws_size,
                              hipStream_t stream) {
  const float* h   = (const float*)d_in[0];
  const float* adj = (const float*)d_in[1];
  const float* W   = (const float*)d_in[2];
  const float* a   = (const float*)d_in[3];
  float* out = (float*)d_out;

  char* ws = (char*)d_ws;
  _Float16* G16        = (_Float16*)ws;                          // 4 MB
  float*    el         = (float*)(ws + 4u * 1024 * 1024);        // 128 KB
  float*    er         = (float*)(ws + 4u * 1024 * 1024 + 128 * 1024);
  float*    gsum       = (float*)(ws + 4u * 1024 * 1024 + 256 * 1024);  // 2 KB
  unsigned* ermax_keys = (unsigned*)(ws + 4u * 1024 * 1024 + 258 * 1024);

  // zero gsum (512 floats) + ermax keys (8 uints; key 0 decodes below any real er)
  hipMemsetAsync(gsum, 0, 2048 + 32, stream);
  gemm_fused<<<dim3(64, 8), 256, 0, stream>>>(h, W, a, G16, el, er, gsum, ermax_keys);
  attn_sparse<<<dim3(N_NODES), 256, 0, stream>>>(adj, G16, el, er, ermax_keys, gsum, out);
}